// Round 1
// baseline (224.355 us; speedup 1.0000x reference)
//
#include <hip/hip_runtime.h>
#include <hip/hip_bf16.h>

// Problem constants
#define B_    8
#define CIN   256
#define H_    32
#define W_    32
#define KS_   32
#define NH_   8
#define KK_   5      // kernel K=5
#define PAD_  2
#define COUT  768    // KS*3*NH
#define G_    24     // 3*NH
#define OHW   32     // OH = OW = 32
#define EPS_  1e-5f

// ---------------- Kernel 1: 1x1 conv as GEMM ----------------
// attn[(b*COUT + o)*1024 + hw] = sum_c x[(b*CIN+c)*1024 + hw] * w[o*CIN+c] + bias[o]
// M = COUT = 768, N = B*1024 = 8192, K = 256
__launch_bounds__(256)
__global__ void conv_gemm(const float* __restrict__ x, const float* __restrict__ w,
                          const float* __restrict__ bias, float* __restrict__ attn) {
    const int nb = blockIdx.x;   // 128 tiles of 64 pixels
    const int mb = blockIdx.y;   // 12 tiles of 64 outputs
    const int n0 = nb * 64;
    const int m0 = mb * 64;
    const int b  = n0 >> 10;
    const int hw0 = n0 & 1023;

    __shared__ float As[16][68];
    __shared__ float Bs[16][68];

    const int t  = threadIdx.x;
    const int tx = t & 15;       // n micro
    const int ty = t >> 4;       // m micro

    float acc[4][4] = {};

    const float* xb = x + (size_t)b * (CIN * 1024) + hw0;

    for (int k0 = 0; k0 < CIN; k0 += 16) {
        // Load A tile (64 m x 16 k), transposed into As[k][m]
        {
            const int m  = t >> 2;
            const int kq = (t & 3) * 4;
            const float4 v = *(const float4*)(w + (size_t)(m0 + m) * CIN + k0 + kq);
            As[kq + 0][m] = v.x; As[kq + 1][m] = v.y;
            As[kq + 2][m] = v.z; As[kq + 3][m] = v.w;
        }
        // Load B tile (16 k x 64 n)
        {
            const int kk = t >> 4;
            const int nq = (t & 15) * 4;
            const float4 v = *(const float4*)(xb + (size_t)(k0 + kk) * 1024 + nq);
            *(float4*)&Bs[kk][nq] = v;
        }
        __syncthreads();
        #pragma unroll
        for (int kk = 0; kk < 16; ++kk) {
            float a[4], bv[4];
            #pragma unroll
            for (int u = 0; u < 4; ++u) a[u]  = As[kk][ty * 4 + u];
            #pragma unroll
            for (int u = 0; u < 4; ++u) bv[u] = Bs[kk][tx * 4 + u];
            #pragma unroll
            for (int i2 = 0; i2 < 4; ++i2)
                #pragma unroll
                for (int j2 = 0; j2 < 4; ++j2)
                    acc[i2][j2] += a[i2] * bv[j2];
        }
        __syncthreads();
    }

    #pragma unroll
    for (int i2 = 0; i2 < 4; ++i2) {
        const int m = m0 + ty * 4 + i2;
        const float bb = bias[m];
        float4 o;
        o.x = acc[i2][0] + bb; o.y = acc[i2][1] + bb;
        o.z = acc[i2][2] + bb; o.w = acc[i2][3] + bb;
        *(float4*)(attn + ((size_t)b * COUT + m) * 1024 + hw0 + tx * 4) = o;
    }
}

// ---------------- Kernel 2: per-(b, kh, kw, group) mean / rstd ----------------
// Window (kh,kw) covers attn rows max(0,kh-2)..min(31,kh+29), cols likewise.
// Count is always 32*32*32 = 32768 (padding zeros count but contribute 0).
__launch_bounds__(256)
__global__ void gn_stats(const float* __restrict__ attn,
                         float* __restrict__ meanArr, float* __restrict__ rstdArr) {
    const int bg = blockIdx.x;       // B_*G_ = 192
    const int b = bg / G_;
    const int g = bg % G_;

    __shared__ float pl[32][33];
    __shared__ float rp[32][5];
    __shared__ float rp2[32][5];

    const int t = threadIdx.x;
    float wsum = 0.f, wsq = 0.f;     // per-thread (t<25) window accumulators

    for (int cc = 0; cc < 32; ++cc) {
        const float* src = attn + ((size_t)(b * COUT + g * 32 + cc)) * 1024;
        #pragma unroll
        for (int it = 0; it < 4; ++it) {
            const int idx = it * 256 + t;
            pl[idx >> 5][idx & 31] = src[idx];
        }
        __syncthreads();
        if (t < 32) {
            float full = 0.f, fsq = 0.f;
            #pragma unroll
            for (int x = 0; x < 32; ++x) {
                const float v = pl[t][x];
                full += v; fsq += v * v;
            }
            const float r0 = pl[t][0], r1 = pl[t][1], r30 = pl[t][30], r31 = pl[t][31];
            rp[t][0] = full - r30 - r31;
            rp[t][1] = full - r31;
            rp[t][2] = full;
            rp[t][3] = full - r0;
            rp[t][4] = full - r0 - r1;
            rp2[t][0] = fsq - r30 * r30 - r31 * r31;
            rp2[t][1] = fsq - r31 * r31;
            rp2[t][2] = fsq;
            rp2[t][3] = fsq - r0 * r0;
            rp2[t][4] = fsq - r0 * r0 - r1 * r1;
        }
        __syncthreads();
        if (t < 25) {
            const int kh = t / 5, kw = t % 5;
            float cs = 0.f, cs2 = 0.f;
            #pragma unroll
            for (int y = 0; y < 32; ++y) { cs += rp[y][kw]; cs2 += rp2[y][kw]; }
            if (kh == 0)      { cs -= rp[30][kw] + rp[31][kw]; cs2 -= rp2[30][kw] + rp2[31][kw]; }
            else if (kh == 1) { cs -= rp[31][kw];              cs2 -= rp2[31][kw]; }
            else if (kh == 3) { cs -= rp[0][kw];               cs2 -= rp2[0][kw]; }
            else if (kh == 4) { cs -= rp[0][kw] + rp[1][kw];   cs2 -= rp2[0][kw] + rp2[1][kw]; }
            wsum += cs; wsq += cs2;
        }
        __syncthreads();
    }
    if (t < 25) {
        const float inv_n = 1.f / 32768.f;
        const float mean = wsum * inv_n;
        const float var  = wsq * inv_n - mean * mean;
        meanArr[bg * 25 + t] = mean;
        rstdArr[bg * 25 + t] = rsqrtf(var + EPS_);
    }
}

// ---------------- Kernel 3: local attention ----------------
// One thread per (b, n, i, j). Block = 256 threads covers a quarter of a
// (b,n) 32x32 plane so all threads share the same head stats (LDS).
__launch_bounds__(256)
__global__ void local_attn(const float* __restrict__ attn,
                           const float* __restrict__ meanArr, const float* __restrict__ rstdArr,
                           const float* __restrict__ gn_w, const float* __restrict__ gn_b,
                           float* __restrict__ out) {
    const int blk = blockIdx.x;          // 256 blocks
    const int bn = blk >> 2;             // [0,64)
    const int b = bn >> 3;
    const int n = bn & 7;
    const int t = threadIdx.x;
    const int pix = (blk & 3) * 256 + t; // [0,1024)
    const int i = pix >> 5;
    const int j = pix & 31;

    __shared__ float s_meanK[25], s_rstdK[25];
    __shared__ float s_meanQ[25], s_rstdQ[25];
    __shared__ float s_meanV[25], s_rstdV[25];
    __shared__ float s_gw[96], s_gb[96];

    if (t < 25) {
        const int gk = (b * G_ + n * 3) * 25 + t;
        s_meanK[t] = meanArr[gk];          s_rstdK[t] = rstdArr[gk];
        s_meanQ[t] = meanArr[gk + 25];     s_rstdQ[t] = rstdArr[gk + 25];
        s_meanV[t] = meanArr[gk + 50];     s_rstdV[t] = rstdArr[gk + 50];
    }
    if (t < 96) {
        s_gw[t] = gn_w[n * 96 + t];
        s_gb[t] = gn_b[n * 96 + t];
    }
    __syncthreads();

    const float* aB = attn + (size_t)b * COUT * 1024 + (size_t)n * 96 * 1024;
    const int by = i - PAD_;
    const int bx = j - PAD_;

    float sal[25];
    #pragma unroll
    for (int p = 0; p < 25; ++p) sal[p] = 0.f;

    for (int k = 0; k < 32; ++k) {
        // ---- q_k = gw_q * (1/25) * sum_p (raw_q - meanQ[p]) * rstdQ[p] + gb_q
        const float* pq = aB + (size_t)(32 + k) * 1024;
        float qk = 0.f;
        #pragma unroll
        for (int kh = 0; kh < 5; ++kh) {
            const int y = by + kh;
            const bool yok = ((unsigned)y < 32u);
            #pragma unroll
            for (int kw = 0; kw < 5; ++kw) {
                const int x = bx + kw;
                const int p = kh * 5 + kw;
                const float raw = (yok && (unsigned)x < 32u) ? pq[y * 32 + x] : 0.f;
                qk += (raw - s_meanQ[p]) * s_rstdQ[p];
            }
        }
        qk = s_gw[32 + k] * (qk * 0.04f) + s_gb[32 + k];   // /25

        // ---- sal[p] += q_k * keyn[k][p]
        const float* pk = aB + (size_t)k * 1024;
        const float gwk = s_gw[k], gbk = s_gb[k];
        #pragma unroll
        for (int kh = 0; kh < 5; ++kh) {
            const int y = by + kh;
            const bool yok = ((unsigned)y < 32u);
            #pragma unroll
            for (int kw = 0; kw < 5; ++kw) {
                const int x = bx + kw;
                const int p = kh * 5 + kw;
                const float raw = (yok && (unsigned)x < 32u) ? pk[y * 32 + x] : 0.f;
                const float kn = (raw - s_meanK[p]) * s_rstdK[p] * gwk + gbk;
                sal[p] += qk * kn;
            }
        }
    }

    // softmax over 25 (with the 1/sqrt(32) scale)
    const float scale = 0.17677669529663687f;
    float mmax = -3.4e38f;
    #pragma unroll
    for (int p = 0; p < 25; ++p) { sal[p] *= scale; mmax = fmaxf(mmax, sal[p]); }
    float ssum = 0.f;
    #pragma unroll
    for (int p = 0; p < 25; ++p) { sal[p] = __expf(sal[p] - mmax); ssum += sal[p]; }
    const float rs = 1.f / ssum;
    #pragma unroll
    for (int p = 0; p < 25; ++p) sal[p] *= rs;

    // out[v] = sum_p vn[v][p] * mask[p]
    for (int v = 0; v < 32; ++v) {
        const float* pv = aB + (size_t)(64 + v) * 1024;
        const float gwv = s_gw[64 + v], gbv = s_gb[64 + v];
        float acc = 0.f;
        #pragma unroll
        for (int kh = 0; kh < 5; ++kh) {
            const int y = by + kh;
            const bool yok = ((unsigned)y < 32u);
            #pragma unroll
            for (int kw = 0; kw < 5; ++kw) {
                const int x = bx + kw;
                const int p = kh * 5 + kw;
                const float raw = (yok && (unsigned)x < 32u) ? pv[y * 32 + x] : 0.f;
                const float vn = (raw - s_meanV[p]) * s_rstdV[p] * gwv + gbv;
                acc += vn * sal[p];
            }
        }
        out[(((size_t)b * 256 + n * 32 + v) * 32 + i) * 32 + j] = acc;
    }
}

extern "C" void kernel_launch(void* const* d_in, const int* in_sizes, int n_in,
                              void* d_out, int out_size, void* d_ws, size_t ws_size,
                              hipStream_t stream) {
    const float* x      = (const float*)d_in[0];  // (8,256,32,32)
    const float* conv_w = (const float*)d_in[1];  // (768,256)
    const float* conv_b = (const float*)d_in[2];  // (768,)
    const float* gn_w   = (const float*)d_in[3];  // (768,)
    const float* gn_b   = (const float*)d_in[4];  // (768,)
    float* out = (float*)d_out;                   // (8,256,32,32) fp32

    // workspace layout (floats): attn[6291456] | mean[4800] | rstd[4800]
    float* attn    = (float*)d_ws;
    float* meanArr = attn + (size_t)B_ * COUT * 1024;
    float* rstdArr = meanArr + B_ * G_ * 25;

    conv_gemm<<<dim3(128, 12), 256, 0, stream>>>(x, conv_w, conv_b, attn);
    gn_stats<<<B_ * G_, 256, 0, stream>>>(attn, meanArr, rstdArr);
    local_attn<<<256, 256, 0, stream>>>(attn, meanArr, rstdArr, gn_w, gn_b, out);
}

// Round 2
// 161.506 us; speedup vs baseline: 1.3891x; 1.3891x over previous
//
#include <hip/hip_runtime.h>
#include <hip/hip_bf16.h>

#define B_    8
#define CIN   256
#define COUT  768
#define G_    24
#define NH_   8
#define PW    36
#define PLANE 1296       // 36*36 padded plane
#define EPS_  1e-5f

typedef float f32x4 __attribute__((ext_vector_type(4)));
typedef short s16x8 __attribute__((ext_vector_type(8)));
typedef unsigned short ushort_t;

static __device__ __forceinline__ ushort_t f2bf(float f) {
    union { float f; unsigned u; } a; a.f = f;
    const unsigned u = a.u;
    const unsigned r = u + 0x7FFFu + ((u >> 16) & 1u);   // round-to-nearest-even
    return (ushort_t)(r >> 16);
}

// ---------------- Kernel 0: prep (Xt transpose+cvt, Wt cvt, border zero) ----
__launch_bounds__(256)
__global__ void prep(const float* __restrict__ x, const float* __restrict__ w,
                     ushort_t* __restrict__ Xt, ushort_t* __restrict__ Wt,
                     float* __restrict__ attn) {
    const int z = blockIdx.x;
    const int t = threadIdx.x;
    if (z < 2048) {
        // transpose x[b][k][n] (256x1024 per b) -> Xt[b][n][k] bf16, 32x32 tiles
        __shared__ ushort_t tile[32][33];
        const int b  = z >> 8, rem = z & 255;
        const int k0 = (rem >> 5) * 32, n0 = (rem & 31) * 32;
        const int kk = t >> 5, nn = t & 31;
        #pragma unroll
        for (int it = 0; it < 4; ++it) {
            const int kr = kk + it * 8;
            tile[kr][nn] = f2bf(x[((size_t)(b * 256 + k0 + kr)) * 1024 + n0 + nn]);
        }
        __syncthreads();
        const int kk2 = t & 31, nb = t >> 5;
        #pragma unroll
        for (int it = 0; it < 4; ++it) {
            const int nr = nb + it * 8;
            Xt[((size_t)(b * 1024 + n0 + nr)) * 256 + k0 + kk2] = tile[kk2][nr];
        }
    } else if (z < 2816) {
        const int idx = (z - 2048) * 256 + t;   // 768*256 = 196608
        Wt[idx] = f2bf(w[idx]);
    } else {
        // zero the 2-wide border of one padded plane (6144 planes)
        const int plane = z - 2816;
        float* base = attn + (size_t)plane * PLANE;
        if (t < 144) {
            const int half = t / 72;
            const int r = t - half * 72;
            const int y = (half ? 34 : 0) + r / 36;
            const int xx = r % 36;
            base[y * 36 + xx] = 0.f;
        } else if (t < 272) {
            const int idx = t - 144;
            const int y = 2 + (idx >> 2);
            const int c = idx & 3;
            const int xx = (c < 2) ? c : 32 + c;
            base[y * 36 + xx] = 0.f;
        }
    }
}

// ---------------- Kernel 1: bf16 MFMA GEMM -> padded attn ----------------
// C[m,n] = sum_k Wt[m,k] * Xt[n,k], M=768, N=8192 (b*1024+pix), K=256
__launch_bounds__(256)
__global__ void conv_gemm(const ushort_t* __restrict__ Wt, const ushort_t* __restrict__ Xt,
                          const float* __restrict__ bias, float* __restrict__ attn) {
    const int t = threadIdx.x;
    const int wv = t >> 6, lane = t & 63;
    const int q = lane >> 4, l15 = lane & 15;
    const int m0 = blockIdx.y * 64 + wv * 16;      // wave's 16-row m slice
    const int n_t = blockIdx.x * 64;
    const int b = n_t >> 10, nl0 = n_t & 1023;

    const ushort_t* aP = Wt + (size_t)(m0 + l15) * 256 + q * 8;
    const ushort_t* bP = Xt + (size_t)(b * 1024 + nl0 + l15) * 256 + q * 8;

    f32x4 acc[4] = {{0,0,0,0},{0,0,0,0},{0,0,0,0},{0,0,0,0}};
    #pragma unroll
    for (int k0 = 0; k0 < 256; k0 += 32) {
        const s16x8 a  = *(const s16x8*)(aP + k0);
        const s16x8 b0 = *(const s16x8*)(bP + k0);
        const s16x8 b1 = *(const s16x8*)(bP + 16 * 256 + k0);
        const s16x8 b2 = *(const s16x8*)(bP + 32 * 256 + k0);
        const s16x8 b3 = *(const s16x8*)(bP + 48 * 256 + k0);
        acc[0] = __builtin_amdgcn_mfma_f32_16x16x32_bf16(a, b0, acc[0], 0, 0, 0);
        acc[1] = __builtin_amdgcn_mfma_f32_16x16x32_bf16(a, b1, acc[1], 0, 0, 0);
        acc[2] = __builtin_amdgcn_mfma_f32_16x16x32_bf16(a, b2, acc[2], 0, 0, 0);
        acc[3] = __builtin_amdgcn_mfma_f32_16x16x32_bf16(a, b3, acc[3], 0, 0, 0);
    }
    // D[m][n]: m = m0 + q*4 + r, n = nl0 + j*16 + l15
    float bb[4];
    #pragma unroll
    for (int r = 0; r < 4; ++r) bb[r] = bias[m0 + q * 4 + r];
    #pragma unroll
    for (int j = 0; j < 4; ++j) {
        const int n = nl0 + j * 16 + l15;
        const int y = n >> 5, xx = n & 31;
        float* o = attn + ((size_t)(b * COUT + m0 + q * 4)) * PLANE + (y + 2) * 36 + xx + 2;
        #pragma unroll
        for (int r = 0; r < 4; ++r)
            o[(size_t)r * PLANE] = acc[j][r] + bb[r];
    }
}

// ---------------- Kernel 2: GN stats (channel-sum first) ----------------
__launch_bounds__(1024)
__global__ void gn_stats(const float* __restrict__ attn,
                         float* __restrict__ meanArr, float* __restrict__ rstdArr) {
    const int bg = blockIdx.x;          // 192
    const int b = bg / G_, g = bg % G_;
    const int t = threadIdx.x;          // 1024: one interior pixel each
    const int y = t >> 5, xx = t & 31;

    __shared__ float pl[32][33], pl2[32][33];
    __shared__ float rp[32][5], rp2[32][5];

    const float* src = attn + ((size_t)(b * COUT + g * 32)) * PLANE + (y + 2) * 36 + xx + 2;
    float P = 0.f, P2 = 0.f;
    #pragma unroll
    for (int c = 0; c < 32; ++c) {
        const float v = src[(size_t)c * PLANE];
        P += v; P2 += v * v;
    }
    pl[y][xx] = P; pl2[y][xx] = P2;
    __syncthreads();

    if (t < 32) {
        float full = 0.f;
        #pragma unroll
        for (int x2 = 0; x2 < 32; ++x2) full += pl[t][x2];
        const float r0 = pl[t][0], r1 = pl[t][1], r30 = pl[t][30], r31 = pl[t][31];
        rp[t][0] = full - r30 - r31; rp[t][1] = full - r31; rp[t][2] = full;
        rp[t][3] = full - r0;        rp[t][4] = full - r0 - r1;
    } else if (t >= 64 && t < 96) {
        const int tt = t - 64;
        float full = 0.f;
        #pragma unroll
        for (int x2 = 0; x2 < 32; ++x2) full += pl2[tt][x2];
        const float r0 = pl2[tt][0], r1 = pl2[tt][1], r30 = pl2[tt][30], r31 = pl2[tt][31];
        rp2[tt][0] = full - r30 - r31; rp2[tt][1] = full - r31; rp2[tt][2] = full;
        rp2[tt][3] = full - r0;        rp2[tt][4] = full - r0 - r1;
    }
    __syncthreads();

    if (t < 25) {
        const int kw = t % 5, kh = t / 5;
        float cs = 0.f, cs2 = 0.f;
        #pragma unroll
        for (int yy = 0; yy < 32; ++yy) { cs += rp[yy][kw]; cs2 += rp2[yy][kw]; }
        if (kh == 0)      { cs -= rp[30][kw] + rp[31][kw]; cs2 -= rp2[30][kw] + rp2[31][kw]; }
        else if (kh == 1) { cs -= rp[31][kw];              cs2 -= rp2[31][kw]; }
        else if (kh == 3) { cs -= rp[0][kw];               cs2 -= rp2[0][kw]; }
        else if (kh == 4) { cs -= rp[0][kw] + rp[1][kw];   cs2 -= rp2[0][kw] + rp2[1][kw]; }
        const float inv_n = 1.f / 32768.f;
        const float mean = cs * inv_n;
        const float var  = cs2 * inv_n - mean * mean;
        meanArr[bg * 25 + t] = mean;
        rstdArr[bg * 25 + t] = rsqrtf(var + EPS_);
    }
}

// ---------------- Kernel 3: local attention (folded GN, k/v split) ----------
__launch_bounds__(256)
__global__ void local_attn(const float* __restrict__ attn,
                           const float* __restrict__ meanArr, const float* __restrict__ rstdArr,
                           const float* __restrict__ gn_w, const float* __restrict__ gn_b,
                           float* __restrict__ out) {
    const int blk = blockIdx.x;          // 512
    const int bn = blk >> 3;
    const int b = bn >> 3, n = bn & 7;
    const int sub = blk & 3 ? blk & 7 : blk & 7;  // (kept simple below)
    const int t = threadIdx.x;
    const int half = t >> 7, tp = t & 127;
    const int pix = (blk & 7) * 128 + tp;
    const int i = pix >> 5, j = pix & 31;

    __shared__ float s_rq[25], s_mq[25];
    __shared__ float s_rk[25], s_ck[25];
    __shared__ float s_rv[25], s_cv[25];
    __shared__ float s_gw[96], s_gb[96];
    __shared__ float ex[256][27];

    if (t < 25) {
        const int gk = (b * G_ + n * 3) * 25 + t;
        const float mK = meanArr[gk],      rK = rstdArr[gk];
        const float mQ = meanArr[gk + 25], rQ = rstdArr[gk + 25];
        const float mV = meanArr[gk + 50], rV = rstdArr[gk + 50];
        s_rk[t] = rK; s_ck[t] = mK * rK;
        s_rq[t] = rQ; s_mq[t] = mQ * rQ;
        s_rv[t] = rV; s_cv[t] = mV * rV;
    }
    if (t < 96) { s_gw[t] = gn_w[n * 96 + t]; s_gb[t] = gn_b[n * 96 + t]; }
    __syncthreads();

    float rq[25], cQ = 0.f;
    #pragma unroll
    for (int p = 0; p < 25; ++p) { rq[p] = s_rq[p]; cQ += s_mq[p]; }

    const float* aB = attn + (size_t)(b * COUT + n * 96) * PLANE;
    const int po = i * 36 + j;           // window (kh,kw) -> po + kh*36 + kw

    float sal[25];
    #pragma unroll
    for (int p = 0; p < 25; ++p) sal[p] = 0.f;
    float sumQ2 = 0.f, sumQB = 0.f;

    #pragma unroll 2
    for (int kk = 0; kk < 16; ++kk) {
        const int k = half * 16 + kk;
        const float* pq = aB + (size_t)(32 + k) * PLANE + po;
        float qa = 0.f;
        #pragma unroll
        for (int kh = 0; kh < 5; ++kh)
            #pragma unroll
            for (int kw = 0; kw < 5; ++kw)
                qa += rq[kh * 5 + kw] * pq[kh * 36 + kw];
        const float qk  = s_gw[32 + k] * ((qa - cQ) * 0.04f) + s_gb[32 + k];
        const float qk2 = qk * s_gw[k];
        sumQ2 += qk2; sumQB += qk * s_gb[k];
        const float* pk = aB + (size_t)k * PLANE + po;
        #pragma unroll
        for (int kh = 0; kh < 5; ++kh)
            #pragma unroll
            for (int kw = 0; kw < 5; ++kw)
                sal[kh * 5 + kw] += qk2 * pk[kh * 36 + kw];
    }

    // combine the two k-halves
    #pragma unroll
    for (int p = 0; p < 25; ++p) ex[t][p] = sal[p];
    ex[t][25] = sumQ2; ex[t][26] = sumQB;
    __syncthreads();
    const int pt = t ^ 128;
    #pragma unroll
    for (int p = 0; p < 25; ++p) sal[p] += ex[pt][p];
    sumQ2 += ex[pt][25]; sumQB += ex[pt][26];

    #pragma unroll
    for (int p = 0; p < 25; ++p) sal[p] = s_rk[p] * sal[p] - s_ck[p] * sumQ2 + sumQB;

    const float scale = 0.17677669529663687f;  // 1/sqrt(32)
    float mmax = -3.4e38f;
    #pragma unroll
    for (int p = 0; p < 25; ++p) { sal[p] *= scale; mmax = fmaxf(mmax, sal[p]); }
    float ssum = 0.f;
    #pragma unroll
    for (int p = 0; p < 25; ++p) { sal[p] = __expf(sal[p] - mmax); ssum += sal[p]; }
    const float rs = 1.f / ssum;
    float w2[25]; float cV2 = 0.f;
    #pragma unroll
    for (int p = 0; p < 25; ++p) {
        const float m = sal[p] * rs;
        w2[p] = m * s_rv[p];
        cV2 += m * s_cv[p];
    }

    #pragma unroll 4
    for (int vv = 0; vv < 16; ++vv) {
        const int v = half * 16 + vv;
        const float* pv = aB + (size_t)(64 + v) * PLANE + po;
        float acc = 0.f;
        #pragma unroll
        for (int kh = 0; kh < 5; ++kh)
            #pragma unroll
            for (int kw = 0; kw < 5; ++kw)
                acc += w2[kh * 5 + kw] * pv[kh * 36 + kw];
        out[((size_t)(b * 256 + n * 32 + v) * 32 + i) * 32 + j] =
            s_gw[64 + v] * acc + (s_gb[64 + v] - s_gw[64 + v] * cV2);
    }
}

extern "C" void kernel_launch(void* const* d_in, const int* in_sizes, int n_in,
                              void* d_out, int out_size, void* d_ws, size_t ws_size,
                              hipStream_t stream) {
    const float* x      = (const float*)d_in[0];
    const float* conv_w = (const float*)d_in[1];
    const float* conv_b = (const float*)d_in[2];
    const float* gn_w   = (const float*)d_in[3];
    const float* gn_b   = (const float*)d_in[4];
    float* out = (float*)d_out;

    // ws layout: attn padded fp32 | Xt bf16 | Wt bf16 | mean | rstd  (~36.5 MB)
    float*    attn    = (float*)d_ws;                       // 8*768*1296 = 7,962,624 f
    ushort_t* Xt      = (ushort_t*)(attn + 7962624);        // 8*1024*256
    ushort_t* Wt      = Xt + 2097152;                       // 768*256
    float*    meanArr = (float*)(Wt + 196608);              // 4800
    float*    rstdArr = meanArr + 4800;                     // 4800

    prep<<<8960, 256, 0, stream>>>(x, conv_w, Xt, Wt, attn);
    conv_gemm<<<dim3(128, 12), 256, 0, stream>>>(Wt, Xt, conv_b, attn);
    gn_stats<<<192, 1024, 0, stream>>>(attn, meanArr, rstdArr);
    local_attn<<<512, 256, 0, stream>>>(attn, meanArr, rstdArr, gn_w, gn_b, out);
}

// Round 3
// 139.123 us; speedup vs baseline: 1.6126x; 1.1609x over previous
//
#include <hip/hip_runtime.h>
#include <hip/hip_bf16.h>

#define B_    8
#define CIN   256
#define COUT  768
#define G_    24
#define PLANE 1296       // 36*36 padded plane
#define EPS_  1e-5f

typedef float f32x4 __attribute__((ext_vector_type(4)));
typedef short s16x8 __attribute__((ext_vector_type(8)));
typedef unsigned short ushort_t;
typedef unsigned short u16x4 __attribute__((ext_vector_type(4)));

static __device__ __forceinline__ ushort_t f2bf(float f) {
    union { float f; unsigned u; } a; a.f = f;
    const unsigned u = a.u;
    const unsigned r = u + 0x7FFFu + ((u >> 16) & 1u);   // round-to-nearest-even
    return (ushort_t)(r >> 16);
}
static __device__ __forceinline__ float bf2f(ushort_t h) {
    union { unsigned u; float f; } a; a.u = ((unsigned)h) << 16; return a.f;
}

// ---------------- Kernel 0: prep (Xt transpose+cvt, Wt cvt, border zero) ----
__launch_bounds__(256)
__global__ void prep(const float* __restrict__ x, const float* __restrict__ w,
                     ushort_t* __restrict__ Xt, ushort_t* __restrict__ Wt,
                     ushort_t* __restrict__ attn) {
    const int z = blockIdx.x;
    const int t = threadIdx.x;
    if (z < 2048) {
        // transpose x[b][k][n] (256x1024 per b) -> Xt[b][n][k] bf16, 32x32 tiles
        __shared__ ushort_t tile[32][33];
        const int b  = z >> 8, rem = z & 255;
        const int k0 = (rem >> 5) * 32, n0 = (rem & 31) * 32;
        const int kk = t >> 5, nn = t & 31;
        #pragma unroll
        for (int it = 0; it < 4; ++it) {
            const int kr = kk + it * 8;
            tile[kr][nn] = f2bf(x[((size_t)(b * 256 + k0 + kr)) * 1024 + n0 + nn]);
        }
        __syncthreads();
        const int kk2 = t & 31, nb = t >> 5;
        #pragma unroll
        for (int it = 0; it < 4; ++it) {
            const int nr = nb + it * 8;
            Xt[((size_t)(b * 1024 + n0 + nr)) * 256 + k0 + kk2] = tile[kk2][nr];
        }
    } else if (z < 2816) {
        const int idx = (z - 2048) * 256 + t;   // 768*256 = 196608
        Wt[idx] = f2bf(w[idx]);
    } else {
        // zero the 2-wide border of one padded plane (6144 planes, 272 elems)
        const int plane = z - 2816;
        ushort_t* base = attn + (size_t)plane * PLANE;
        for (int idx = t; idx < 272; idx += 256) {
            int y, xx;
            if (idx < 144) {
                const int half = idx / 72;
                const int r2 = idx - half * 72;
                y = (half ? 34 : 0) + r2 / 36;
                xx = r2 % 36;
            } else {
                const int q2 = idx - 144;
                y = 2 + (q2 >> 2);
                const int c = q2 & 3;
                xx = (c < 2) ? c : (32 + c);
            }
            base[y * 36 + xx] = 0;
        }
    }
}

// ---------------- Kernel 1: bf16 MFMA GEMM -> padded bf16 attn ----------------
// C[m,n] = sum_k Wt[m,k] * Xt[n,k], M=768, N=8192 (b*1024+pix), K=256
__launch_bounds__(256)
__global__ void conv_gemm(const ushort_t* __restrict__ Wt, const ushort_t* __restrict__ Xt,
                          const float* __restrict__ bias, ushort_t* __restrict__ attn) {
    const int t = threadIdx.x;
    const int wv = t >> 6, lane = t & 63;
    const int q = lane >> 4, l15 = lane & 15;
    const int m0 = blockIdx.y * 64 + wv * 16;
    const int n_t = blockIdx.x * 64;
    const int b = n_t >> 10, nl0 = n_t & 1023;

    const ushort_t* aP = Wt + (size_t)(m0 + l15) * 256 + q * 8;
    const ushort_t* bP = Xt + (size_t)(b * 1024 + nl0 + l15) * 256 + q * 8;

    f32x4 acc[4] = {{0,0,0,0},{0,0,0,0},{0,0,0,0},{0,0,0,0}};
    #pragma unroll
    for (int k0 = 0; k0 < 256; k0 += 32) {
        const s16x8 a  = *(const s16x8*)(aP + k0);
        const s16x8 b0 = *(const s16x8*)(bP + k0);
        const s16x8 b1 = *(const s16x8*)(bP + 16 * 256 + k0);
        const s16x8 b2 = *(const s16x8*)(bP + 32 * 256 + k0);
        const s16x8 b3 = *(const s16x8*)(bP + 48 * 256 + k0);
        acc[0] = __builtin_amdgcn_mfma_f32_16x16x32_bf16(a, b0, acc[0], 0, 0, 0);
        acc[1] = __builtin_amdgcn_mfma_f32_16x16x32_bf16(a, b1, acc[1], 0, 0, 0);
        acc[2] = __builtin_amdgcn_mfma_f32_16x16x32_bf16(a, b2, acc[2], 0, 0, 0);
        acc[3] = __builtin_amdgcn_mfma_f32_16x16x32_bf16(a, b3, acc[3], 0, 0, 0);
    }
    float bb[4];
    #pragma unroll
    for (int r = 0; r < 4; ++r) bb[r] = bias[m0 + q * 4 + r];
    #pragma unroll
    for (int j = 0; j < 4; ++j) {
        const int n = nl0 + j * 16 + l15;
        const int y = n >> 5, xx = n & 31;
        ushort_t* o = attn + ((size_t)(b * COUT + m0 + q * 4)) * PLANE + (y + 2) * 36 + xx + 2;
        #pragma unroll
        for (int r = 0; r < 4; ++r)
            o[(size_t)r * PLANE] = f2bf(acc[j][r] + bb[r]);
    }
}

// ---------------- Kernel 2: GN stats (bf16 input, 4 px/thread) ----------------
__launch_bounds__(256)
__global__ void gn_stats(const ushort_t* __restrict__ attn,
                         float* __restrict__ meanArr, float* __restrict__ rstdArr) {
    const int bg = blockIdx.x;          // 192
    const int b = bg / G_, g = bg % G_;
    const int t = threadIdx.x;
    const int y = t >> 3, x0 = (t & 7) * 4;

    __shared__ float pl[32][33], pl2[32][33];
    __shared__ float rp[32][5], rp2[32][5];

    const ushort_t* src = attn + ((size_t)(b * COUT + g * 32)) * PLANE + (y + 2) * 36 + x0 + 2;
    float P[4] = {0,0,0,0}, S2[4] = {0,0,0,0};
    #pragma unroll 4
    for (int c = 0; c < 32; ++c) {
        const ushort_t* s2 = src + (size_t)c * PLANE;
        const unsigned a0 = *(const unsigned*)(s2);
        const unsigned a1 = *(const unsigned*)(s2 + 2);
        union { unsigned u; float f; } u0, u1, u2, u3;
        u0.u = a0 << 16; u1.u = a0 & 0xffff0000u;
        u2.u = a1 << 16; u3.u = a1 & 0xffff0000u;
        P[0] += u0.f; S2[0] += u0.f * u0.f;
        P[1] += u1.f; S2[1] += u1.f * u1.f;
        P[2] += u2.f; S2[2] += u2.f * u2.f;
        P[3] += u3.f; S2[3] += u3.f * u3.f;
    }
    #pragma unroll
    for (int u = 0; u < 4; ++u) { pl[y][x0 + u] = P[u]; pl2[y][x0 + u] = S2[u]; }
    __syncthreads();

    if (t < 32) {
        float full = 0.f;
        #pragma unroll
        for (int x2 = 0; x2 < 32; ++x2) full += pl[t][x2];
        const float r0 = pl[t][0], r1 = pl[t][1], r30 = pl[t][30], r31 = pl[t][31];
        rp[t][0] = full - r30 - r31; rp[t][1] = full - r31; rp[t][2] = full;
        rp[t][3] = full - r0;        rp[t][4] = full - r0 - r1;
    } else if (t >= 64 && t < 96) {
        const int tt = t - 64;
        float full = 0.f;
        #pragma unroll
        for (int x2 = 0; x2 < 32; ++x2) full += pl2[tt][x2];
        const float r0 = pl2[tt][0], r1 = pl2[tt][1], r30 = pl2[tt][30], r31 = pl2[tt][31];
        rp2[tt][0] = full - r30 - r31; rp2[tt][1] = full - r31; rp2[tt][2] = full;
        rp2[tt][3] = full - r0;        rp2[tt][4] = full - r0 - r1;
    }
    __syncthreads();

    if (t < 25) {
        const int kw = t % 5, kh = t / 5;
        float cs = 0.f, cs2 = 0.f;
        #pragma unroll
        for (int yy = 0; yy < 32; ++yy) { cs += rp[yy][kw]; cs2 += rp2[yy][kw]; }
        if (kh == 0)      { cs -= rp[30][kw] + rp[31][kw]; cs2 -= rp2[30][kw] + rp2[31][kw]; }
        else if (kh == 1) { cs -= rp[31][kw];              cs2 -= rp2[31][kw]; }
        else if (kh == 3) { cs -= rp[0][kw];               cs2 -= rp2[0][kw]; }
        else if (kh == 4) { cs -= rp[0][kw] + rp[1][kw];   cs2 -= rp2[0][kw] + rp2[1][kw]; }
        const float inv_n = 1.f / 32768.f;
        const float mean = cs * inv_n;
        const float var  = cs2 * inv_n - mean * mean;
        meanArr[bg * 25 + t] = mean;
        rstdArr[bg * 25 + t] = rsqrtf(var + EPS_);
    }
}

// ---------------- Kernel 3: local attention, LDS-staged double-buffered ------
// Block = 256 threads = 8-row slab (256 px) of one head. Grid = 256 blocks.
__launch_bounds__(256, 1)
__global__ void local_attn(const ushort_t* __restrict__ attn,
                           const float* __restrict__ meanArr, const float* __restrict__ rstdArr,
                           const float* __restrict__ gn_w, const float* __restrict__ gn_b,
                           float* __restrict__ out) {
    const int blk = blockIdx.x;          // 256
    const int b = blk >> 5;
    const int n = (blk >> 2) & 7;
    const int slab = blk & 3;
    const int i0 = slab * 8;
    const int t = threadIdx.x;
    const int r = t >> 5, j = t & 31;

    __shared__ float Ks[2][432];
    __shared__ float Qs[2][432];
    __shared__ float Vs[2][864];
    __shared__ float s_rq[25], s_mq[25], s_rk[25], s_ck[25], s_rv[25], s_cv[25];
    __shared__ float s_gw[96], s_gb[96];

    if (t < 25) {
        const int gk = (b * G_ + n * 3) * 25 + t;
        const float mK = meanArr[gk],      rK = rstdArr[gk];
        const float mQ = meanArr[gk + 25], rQ = rstdArr[gk + 25];
        const float mV = meanArr[gk + 50], rV = rstdArr[gk + 50];
        s_rk[t] = rK; s_ck[t] = mK * rK;
        s_rq[t] = rQ; s_mq[t] = mQ * rQ;
        s_rv[t] = rV; s_cv[t] = mV * rV;
    }
    if (t < 96) { s_gw[t] = gn_w[n * 96 + t]; s_gb[t] = gn_b[n * 96 + t]; }
    __syncthreads();

    float rq[25]; float cQ = 0.f;
    #pragma unroll
    for (int p = 0; p < 25; ++p) { rq[p] = s_rq[p]; cQ += s_mq[p]; }

    // staging: region = padded rows i0..i0+11, 432 bf16 elems per plane,
    // two planes per step; thread t<216 stages 4 elems (one dwordx2).
    const ushort_t* aB = attn + (size_t)(b * COUT + n * 96) * PLANE + i0 * 36;
    const bool stg = (t < 216);
    const int sp = (t < 108) ? 0 : 1;               // which of the 2 planes
    const int eo = (t < 108) ? t * 4 : (t - 108) * 4;

    u16x4 vr = {0, 0, 0, 0};
    if (stg) vr = *(const u16x4*)(aB + (size_t)(sp * 32) * PLANE + eo);  // K ch0 / Q ch0

    float sal[25];
    #pragma unroll
    for (int p = 0; p < 25; ++p) sal[p] = 0.f;
    float sumQ2 = 0.f, sumQB = 0.f;

    const int base = r * 36 + j;

    for (int ch = 0; ch < 32; ++ch) {
        const int buf = ch & 1;
        if (stg) {
            f32x4 w4 = { bf2f(vr[0]), bf2f(vr[1]), bf2f(vr[2]), bf2f(vr[3]) };
            if (sp == 0) *(f32x4*)&Ks[buf][eo] = w4;
            else         *(f32x4*)&Qs[buf][eo] = w4;
        }
        __syncthreads();
        if (stg) {
            if (ch < 31) vr = *(const u16x4*)(aB + (size_t)(ch + 1 + sp * 32) * PLANE + eo);
            else         vr = *(const u16x4*)(aB + (size_t)(64 + sp) * PLANE + eo);  // V 0/1
        }
        const float* qb = &Qs[buf][base];
        const float* kb = &Ks[buf][base];
        // qa with 5 partial accumulators (shorter dep chain)
        float qa0 = 0.f, qa1 = 0.f, qa2 = 0.f, qa3 = 0.f, qa4 = 0.f;
        #pragma unroll
        for (int kw = 0; kw < 5; ++kw) {
            qa0 += rq[0 * 5 + kw] * qb[0 * 36 + kw];
            qa1 += rq[1 * 5 + kw] * qb[1 * 36 + kw];
            qa2 += rq[2 * 5 + kw] * qb[2 * 36 + kw];
            qa3 += rq[3 * 5 + kw] * qb[3 * 36 + kw];
            qa4 += rq[4 * 5 + kw] * qb[4 * 36 + kw];
        }
        const float qa = (qa0 + qa1) + (qa2 + qa3) + qa4;
        const float qk  = s_gw[32 + ch] * ((qa - cQ) * 0.04f) + s_gb[32 + ch];
        const float qk2 = qk * s_gw[ch];
        sumQ2 += qk2; sumQB += qk * s_gb[ch];
        #pragma unroll
        for (int kh = 0; kh < 5; ++kh)
            #pragma unroll
            for (int kw = 0; kw < 5; ++kw)
                sal[kh * 5 + kw] += qk2 * kb[kh * 36 + kw];
    }

    // fold GN of K, then softmax over 25
    #pragma unroll
    for (int p = 0; p < 25; ++p) sal[p] = s_rk[p] * sal[p] - s_ck[p] * sumQ2 + sumQB;

    const float scale = 0.17677669529663687f;  // 1/sqrt(32)
    float mmax = -3.4e38f;
    #pragma unroll
    for (int p = 0; p < 25; ++p) { sal[p] *= scale; mmax = fmaxf(mmax, sal[p]); }
    float ssum = 0.f;
    #pragma unroll
    for (int p = 0; p < 25; ++p) { sal[p] = __expf(sal[p] - mmax); ssum += sal[p]; }
    const float rs = 1.f / ssum;
    float w2[25]; float cV2 = 0.f;
    #pragma unroll
    for (int p = 0; p < 25; ++p) {
        const float m = sal[p] * rs;
        w2[p] = m * s_rv[p];
        cV2 += m * s_cv[p];
    }

    // V phase: 2 planes per step, 16 steps
    for (int vi = 0; vi < 16; ++vi) {
        const int buf = vi & 1;
        if (stg) {
            f32x4 w4 = { bf2f(vr[0]), bf2f(vr[1]), bf2f(vr[2]), bf2f(vr[3]) };
            *(f32x4*)&Vs[buf][sp * 432 + eo] = w4;
        }
        __syncthreads();
        if (stg && vi < 15)
            vr = *(const u16x4*)(aB + (size_t)(64 + 2 * (vi + 1) + sp) * PLANE + eo);
        #pragma unroll
        for (int h = 0; h < 2; ++h) {
            const float* vb = &Vs[buf][h * 432 + base];
            float a0 = 0.f, a1 = 0.f, a2 = 0.f, a3 = 0.f, a4 = 0.f;
            #pragma unroll
            for (int kw = 0; kw < 5; ++kw) {
                a0 += w2[0 * 5 + kw] * vb[0 * 36 + kw];
                a1 += w2[1 * 5 + kw] * vb[1 * 36 + kw];
                a2 += w2[2 * 5 + kw] * vb[2 * 36 + kw];
                a3 += w2[3 * 5 + kw] * vb[3 * 36 + kw];
                a4 += w2[4 * 5 + kw] * vb[4 * 36 + kw];
            }
            const float acc = (a0 + a1) + (a2 + a3) + a4;
            const int v = vi * 2 + h;
            out[((size_t)(b * 256 + n * 32 + v) * 32 + (i0 + r)) * 32 + j] =
                s_gw[64 + v] * acc + (s_gb[64 + v] - s_gw[64 + v] * cV2);
        }
    }
}

extern "C" void kernel_launch(void* const* d_in, const int* in_sizes, int n_in,
                              void* d_out, int out_size, void* d_ws, size_t ws_size,
                              hipStream_t stream) {
    const float* x      = (const float*)d_in[0];
    const float* conv_w = (const float*)d_in[1];
    const float* conv_b = (const float*)d_in[2];
    const float* gn_w   = (const float*)d_in[3];
    const float* gn_b   = (const float*)d_in[4];
    float* out = (float*)d_out;

    // ws layout: attn bf16 padded | Xt bf16 | Wt bf16 | mean | rstd  (~20.5 MB)
    ushort_t* attn    = (ushort_t*)d_ws;                    // 8*768*1296 = 7,962,624
    ushort_t* Xt      = attn + 7962624;                     // 8*1024*256 = 2,097,152
    ushort_t* Wt      = Xt + 2097152;                       // 768*256 = 196,608
    float*    meanArr = (float*)(Wt + 196608);              // 4800
    float*    rstdArr = meanArr + 4800;                     // 4800

    prep<<<8960, 256, 0, stream>>>(x, conv_w, Xt, Wt, attn);
    conv_gemm<<<dim3(128, 12), 256, 0, stream>>>(Wt, Xt, conv_b, attn);
    gn_stats<<<192, 256, 0, stream>>>(attn, meanArr, rstdArr);
    local_attn<<<256, 256, 0, stream>>>(attn, meanArr, rstdArr, gn_w, gn_b, out);
}

// Round 4
// 133.375 us; speedup vs baseline: 1.6821x; 1.0431x over previous
//
#include <hip/hip_runtime.h>
#include <hip/hip_bf16.h>

#define B_    8
#define CIN   256
#define COUT  768
#define G_    24
#define PW    40         // padded row width (16B-aligned rows)
#define PLANE 1440       // 40*36
#define EPS_  1e-5f

typedef float f32x4 __attribute__((ext_vector_type(4)));
typedef short s16x8 __attribute__((ext_vector_type(8)));
typedef unsigned short ushort_t;
typedef unsigned short u16x4 __attribute__((ext_vector_type(4)));
typedef unsigned long long ull_t;

static __device__ __forceinline__ ushort_t f2bf(float f) {
    union { float f; unsigned u; } a; a.f = f;
    const unsigned u = a.u;
    const unsigned r = u + 0x7FFFu + ((u >> 16) & 1u);
    return (ushort_t)(r >> 16);
}
static __device__ __forceinline__ float bf2f(ushort_t h) {
    union { unsigned u; float f; } a; a.u = ((unsigned)h) << 16; return a.f;
}

// ---------------- Kernel 0: prep (Xt transpose+cvt, Wt cvt) ----------------
__launch_bounds__(256)
__global__ void prep(const float* __restrict__ x, const float* __restrict__ w,
                     ushort_t* __restrict__ Xt, ushort_t* __restrict__ Wt) {
    const int z = blockIdx.x;
    const int t = threadIdx.x;
    if (z < 2048) {
        __shared__ ushort_t tile[32][33];
        const int b  = z >> 8, rem = z & 255;
        const int k0 = (rem >> 5) * 32, n0 = (rem & 31) * 32;
        const int kk = t >> 5, nn = t & 31;
        #pragma unroll
        for (int it = 0; it < 4; ++it) {
            const int kr = kk + it * 8;
            tile[kr][nn] = f2bf(x[((size_t)(b * 256 + k0 + kr)) * 1024 + n0 + nn]);
        }
        __syncthreads();
        const int kk2 = t & 31, nb = t >> 5;
        #pragma unroll
        for (int it = 0; it < 4; ++it) {
            const int nr = nb + it * 8;
            Xt[((size_t)(b * 1024 + n0 + nr)) * 256 + k0 + kk2] = tile[kk2][nr];
        }
    } else {
        const int idx = (z - 2048) * 256 + t;   // 768*256
        Wt[idx] = f2bf(w[idx]);
    }
}

// ---------------- Kernel 1: bf16 MFMA GEMM -> padded bf16 attn + rowAgg ------
// stats order per (b,g,y): 0:lin 1:sq 2:e0 3:e0q 4:e1 5:e1q 6:e30 7:e30q 8:e31 9:e31q
__launch_bounds__(256)
__global__ void conv_gemm(const ushort_t* __restrict__ Wt, const ushort_t* __restrict__ Xt,
                          const float* __restrict__ bias, ushort_t* __restrict__ attn,
                          float* __restrict__ rowAgg) {
    const int t = threadIdx.x;
    const int wv = t >> 6, lane = t & 63;
    const int q = lane >> 4, l15 = lane & 15;
    const int m0 = blockIdx.y * 64;
    const int mw = wv * 16;
    const int n_t = blockIdx.x * 64;
    const int b = n_t >> 10, nl0 = n_t & 1023;
    const int y0 = nl0 >> 5;                    // first of 2 image rows

    __shared__ ushort_t Ct[64][2][44];          // [m][y][40 data+borders, 4 pad]
    __shared__ float red[128][11];

    const ushort_t* aP = Wt + (size_t)(m0 + mw + l15) * 256 + q * 8;
    const ushort_t* bP = Xt + (size_t)(b * 1024 + nl0 + l15) * 256 + q * 8;

    f32x4 acc[4] = {{0,0,0,0},{0,0,0,0},{0,0,0,0},{0,0,0,0}};
    #pragma unroll
    for (int k0 = 0; k0 < 256; k0 += 32) {
        const s16x8 a  = *(const s16x8*)(aP + k0);
        const s16x8 b0 = *(const s16x8*)(bP + k0);
        const s16x8 b1 = *(const s16x8*)(bP + 16 * 256 + k0);
        const s16x8 b2 = *(const s16x8*)(bP + 32 * 256 + k0);
        const s16x8 b3 = *(const s16x8*)(bP + 48 * 256 + k0);
        acc[0] = __builtin_amdgcn_mfma_f32_16x16x32_bf16(a, b0, acc[0], 0, 0, 0);
        acc[1] = __builtin_amdgcn_mfma_f32_16x16x32_bf16(a, b1, acc[1], 0, 0, 0);
        acc[2] = __builtin_amdgcn_mfma_f32_16x16x32_bf16(a, b2, acc[2], 0, 0, 0);
        acc[3] = __builtin_amdgcn_mfma_f32_16x16x32_bf16(a, b3, acc[3], 0, 0, 0);
    }

    // stage bf16 C tile into LDS (borders zeroed)
    float bb[4];
    #pragma unroll
    for (int r = 0; r < 4; ++r) bb[r] = bias[m0 + mw + q * 4 + r];
    #pragma unroll
    for (int j = 0; j < 4; ++j) {
        const int yy = j >> 1, xx = (j & 1) * 16 + l15;
        #pragma unroll
        for (int r = 0; r < 4; ++r)
            Ct[mw + q * 4 + r][yy][2 + xx] = f2bf(acc[j][r] + bb[r]);
    }
    #pragma unroll
    for (int it = 0; it < 2; ++it) {
        const int id = it * 256 + t;            // 512 zero jobs (b32)
        const int m = id >> 3, yy = (id >> 2) & 1, pos = id & 3;
        const int us = (pos == 0) ? 0 : (32 + 2 * pos);   // 0,34,36,38
        *(unsigned*)&Ct[m][yy][us] = 0u;
    }
    __syncthreads();

    // coalesced store: 64m x 2y x 10 s-jobs of 8B
    ushort_t* pb = attn + ((size_t)(b * COUT + m0)) * PLANE;
    #pragma unroll
    for (int it = 0; it < 5; ++it) {
        const int id = it * 256 + t;
        const int m = id / 20, rem = id % 20, yy = rem / 10, s = rem % 10;
        const ull_t v = *(const ull_t*)&Ct[m][yy][s * 4];
        *(ull_t*)(pb + (size_t)m * PLANE + (y0 + yy + 2) * PW + s * 4) = v;
    }
    // top/bottom border rows (zero), only edge blocks
    if (y0 == 0 || y0 == 30) {
        const int rowA = (y0 == 0) ? 0 : 34;
        #pragma unroll
        for (int it = 0; it < 5; ++it) {
            const int id = it * 256 + t;
            const int m = id / 20, rem = id % 20, yy = rem / 10, s = rem % 10;
            *(ull_t*)(pb + (size_t)m * PLANE + (rowA + yy) * PW + s * 4) = 0ull;
        }
    }

    // stats phase-1: (gi,y,c) rows, 128 threads
    if (t < 128) {
        const int gi = t >> 6, yy = (t >> 5) & 1, c = t & 31;
        const int m = gi * 32 + c;
        float lin = 0.f, sq = 0.f, e0 = 0.f, e1 = 0.f, e30 = 0.f, e31 = 0.f;
        #pragma unroll
        for (int u = 0; u < 9; ++u) {           // ushorts 0..35 (borders are 0)
            const ull_t vv = *(const ull_t*)&Ct[m][yy][u * 4];
            const unsigned lo = (unsigned)vv, hi = (unsigned)(vv >> 32);
            union { unsigned u; float f; } f0, f1, f2, f3;
            f0.u = lo << 16; f1.u = lo & 0xffff0000u;
            f2.u = hi << 16; f3.u = hi & 0xffff0000u;
            lin += (f0.f + f1.f) + (f2.f + f3.f);
            sq  += (f0.f * f0.f + f1.f * f1.f) + (f2.f * f2.f + f3.f * f3.f);
            if (u == 0) { e0 = f2.f; e1 = f3.f; }       // ushorts 2,3 = x0,x1
            if (u == 8) { e30 = f0.f; e31 = f1.f; }     // ushorts 32,33 = x30,x31
        }
        red[t][0] = lin; red[t][1] = sq;
        red[t][2] = e0;  red[t][3] = e0 * e0;
        red[t][4] = e1;  red[t][5] = e1 * e1;
        red[t][6] = e30; red[t][7] = e30 * e30;
        red[t][8] = e31; red[t][9] = e31 * e31;
    }
    __syncthreads();
    if (t < 40) {
        const int s = t % 10, gy = t / 10;
        const int gi = gy >> 1, yy = gy & 1;
        float sum = 0.f;
        #pragma unroll
        for (int c = 0; c < 32; ++c) sum += red[gi * 64 + yy * 32 + c][s];
        const int g = blockIdx.y * 2 + gi;
        rowAgg[(((size_t)b * G_ + g) * 32 + (y0 + yy)) * 10 + s] = sum;
    }
}

// ---------------- Kernel 2: tiny stats finalize ----------------
__launch_bounds__(64)
__global__ void gnfin(const float* __restrict__ rowAgg,
                      float* __restrict__ meanArr, float* __restrict__ rstdArr) {
    const int bg = blockIdx.x;       // 192
    const int t = threadIdx.x;
    __shared__ float rp[32][5], rp2[32][5];
    if (t < 32) {
        const float* a = rowAgg + ((size_t)bg * 32 + t) * 10;
        const float S = a[0], Sq = a[1];
        const float e0 = a[2], q0 = a[3], e1 = a[4], q1 = a[5];
        const float e30 = a[6], q30 = a[7], e31 = a[8], q31 = a[9];
        rp[t][0] = S - e30 - e31; rp[t][1] = S - e31; rp[t][2] = S;
        rp[t][3] = S - e0;        rp[t][4] = S - e0 - e1;
        rp2[t][0] = Sq - q30 - q31; rp2[t][1] = Sq - q31; rp2[t][2] = Sq;
        rp2[t][3] = Sq - q0;        rp2[t][4] = Sq - q0 - q1;
    }
    __syncthreads();
    if (t < 25) {
        const int kw = t % 5, kh = t / 5;
        float cs = 0.f, cs2 = 0.f;
        #pragma unroll
        for (int yy = 0; yy < 32; ++yy) { cs += rp[yy][kw]; cs2 += rp2[yy][kw]; }
        if (kh == 0)      { cs -= rp[30][kw] + rp[31][kw]; cs2 -= rp2[30][kw] + rp2[31][kw]; }
        else if (kh == 1) { cs -= rp[31][kw];              cs2 -= rp2[31][kw]; }
        else if (kh == 3) { cs -= rp[0][kw];               cs2 -= rp2[0][kw]; }
        else if (kh == 4) { cs -= rp[0][kw] + rp[1][kw];   cs2 -= rp2[0][kw] + rp2[1][kw]; }
        const float inv_n = 1.f / 32768.f;
        const float mean = cs * inv_n;
        const float var  = cs2 * inv_n - mean * mean;
        meanArr[bg * 25 + t] = mean;
        rstdArr[bg * 25 + t] = rsqrtf(var + EPS_);
    }
}

// ---------------- Kernel 3: local attention, LDS-staged double-buffered ------
__launch_bounds__(256, 1)
__global__ void local_attn(const ushort_t* __restrict__ attn,
                           const float* __restrict__ meanArr, const float* __restrict__ rstdArr,
                           const float* __restrict__ gn_w, const float* __restrict__ gn_b,
                           float* __restrict__ out) {
    const int blk = blockIdx.x;          // 256
    const int b = blk >> 5;
    const int n = (blk >> 2) & 7;
    const int slab = blk & 3;
    const int i0 = slab * 8;
    const int t = threadIdx.x;
    const int r = t >> 5, j = t & 31;

    __shared__ float Ks[2][480];
    __shared__ float Qs[2][480];
    __shared__ float Vs[2][960];
    __shared__ float s_rq[25], s_mq[25], s_rk[25], s_ck[25], s_rv[25], s_cv[25];
    __shared__ float s_gw[96], s_gb[96];

    if (t < 25) {
        const int gk = (b * G_ + n * 3) * 25 + t;
        const float mK = meanArr[gk],      rK = rstdArr[gk];
        const float mQ = meanArr[gk + 25], rQ = rstdArr[gk + 25];
        const float mV = meanArr[gk + 50], rV = rstdArr[gk + 50];
        s_rk[t] = rK; s_ck[t] = mK * rK;
        s_rq[t] = rQ; s_mq[t] = mQ * rQ;
        s_rv[t] = rV; s_cv[t] = mV * rV;
    }
    if (t < 96) { s_gw[t] = gn_w[n * 96 + t]; s_gb[t] = gn_b[n * 96 + t]; }
    __syncthreads();

    float rq[25]; float cQ = 0.f;
    #pragma unroll
    for (int p = 0; p < 25; ++p) { rq[p] = s_rq[p]; cQ += s_mq[p]; }

    // staging: padded rows i0..i0+11 -> 480 elems/plane; 240 stagers x u16x4
    const ushort_t* aB = attn + (size_t)(b * COUT + n * 96) * PLANE + i0 * PW;
    const bool stg = (t < 240);
    const int sp = (t < 120) ? 0 : 1;
    const int eo = ((t < 120) ? t : (t - 120)) * 4;

    u16x4 vr = {0, 0, 0, 0};
    if (stg) vr = *(const u16x4*)(aB + (size_t)(sp * 32) * PLANE + eo);

    float sal[25];
    #pragma unroll
    for (int p = 0; p < 25; ++p) sal[p] = 0.f;
    float sumQ2 = 0.f, sumQB = 0.f;

    const int base = r * PW + j;

    for (int ch = 0; ch < 32; ++ch) {
        const int buf = ch & 1;
        if (stg) {
            f32x4 w4 = { bf2f(vr[0]), bf2f(vr[1]), bf2f(vr[2]), bf2f(vr[3]) };
            if (sp == 0) *(f32x4*)&Ks[buf][eo] = w4;
            else         *(f32x4*)&Qs[buf][eo] = w4;
        }
        __syncthreads();
        if (stg) {
            if (ch < 31) vr = *(const u16x4*)(aB + (size_t)(ch + 1 + sp * 32) * PLANE + eo);
            else         vr = *(const u16x4*)(aB + (size_t)(64 + sp) * PLANE + eo);
        }
        const float* qb = &Qs[buf][base];
        const float* kb = &Ks[buf][base];
        float qa0 = 0.f, qa1 = 0.f, qa2 = 0.f, qa3 = 0.f, qa4 = 0.f;
        #pragma unroll
        for (int kw = 0; kw < 5; ++kw) {
            qa0 += rq[0 * 5 + kw] * qb[0 * PW + kw];
            qa1 += rq[1 * 5 + kw] * qb[1 * PW + kw];
            qa2 += rq[2 * 5 + kw] * qb[2 * PW + kw];
            qa3 += rq[3 * 5 + kw] * qb[3 * PW + kw];
            qa4 += rq[4 * 5 + kw] * qb[4 * PW + kw];
        }
        const float qa = (qa0 + qa1) + (qa2 + qa3) + qa4;
        const float qk  = s_gw[32 + ch] * ((qa - cQ) * 0.04f) + s_gb[32 + ch];
        const float qk2 = qk * s_gw[ch];
        sumQ2 += qk2; sumQB += qk * s_gb[ch];
        #pragma unroll
        for (int kh = 0; kh < 5; ++kh)
            #pragma unroll
            for (int kw = 0; kw < 5; ++kw)
                sal[kh * 5 + kw] += qk2 * kb[kh * PW + kw];
    }

    #pragma unroll
    for (int p = 0; p < 25; ++p) sal[p] = s_rk[p] * sal[p] - s_ck[p] * sumQ2 + sumQB;

    const float scale = 0.17677669529663687f;
    float mmax = -3.4e38f;
    #pragma unroll
    for (int p = 0; p < 25; ++p) { sal[p] *= scale; mmax = fmaxf(mmax, sal[p]); }
    float ssum = 0.f;
    #pragma unroll
    for (int p = 0; p < 25; ++p) { sal[p] = __expf(sal[p] - mmax); ssum += sal[p]; }
    const float rs = 1.f / ssum;
    float w2[25]; float cV2 = 0.f;
    #pragma unroll
    for (int p = 0; p < 25; ++p) {
        const float m = sal[p] * rs;
        w2[p] = m * s_rv[p];
        cV2 += m * s_cv[p];
    }

    for (int vi = 0; vi < 16; ++vi) {
        const int buf = vi & 1;
        if (stg) {
            f32x4 w4 = { bf2f(vr[0]), bf2f(vr[1]), bf2f(vr[2]), bf2f(vr[3]) };
            *(f32x4*)&Vs[buf][sp * 480 + eo] = w4;
        }
        __syncthreads();
        if (stg && vi < 15)
            vr = *(const u16x4*)(aB + (size_t)(64 + 2 * (vi + 1) + sp) * PLANE + eo);
        #pragma unroll
        for (int h = 0; h < 2; ++h) {
            const float* vb = &Vs[buf][h * 480 + base];
            float a0 = 0.f, a1 = 0.f, a2 = 0.f, a3 = 0.f, a4 = 0.f;
            #pragma unroll
            for (int kw = 0; kw < 5; ++kw) {
                a0 += w2[0 * 5 + kw] * vb[0 * PW + kw];
                a1 += w2[1 * 5 + kw] * vb[1 * PW + kw];
                a2 += w2[2 * 5 + kw] * vb[2 * PW + kw];
                a3 += w2[3 * 5 + kw] * vb[3 * PW + kw];
                a4 += w2[4 * 5 + kw] * vb[4 * PW + kw];
            }
            const float acc = (a0 + a1) + (a2 + a3) + a4;
            const int v = vi * 2 + h;
            out[((size_t)(b * 256 + n * 32 + v) * 32 + (i0 + r)) * 32 + j] =
                s_gw[64 + v] * acc + (s_gb[64 + v] - s_gw[64 + v] * cV2);
        }
    }
}

extern "C" void kernel_launch(void* const* d_in, const int* in_sizes, int n_in,
                              void* d_out, int out_size, void* d_ws, size_t ws_size,
                              hipStream_t stream) {
    const float* x      = (const float*)d_in[0];
    const float* conv_w = (const float*)d_in[1];
    const float* conv_b = (const float*)d_in[2];
    const float* gn_w   = (const float*)d_in[3];
    const float* gn_b   = (const float*)d_in[4];
    float* out = (float*)d_out;

    // ws: attn bf16 (8*768*1440) | Xt bf16 | Wt bf16 | rowAgg f32 | mean | rstd
    ushort_t* attn    = (ushort_t*)d_ws;                    // 8,847,360 ushorts
    ushort_t* Xt      = attn + 8847360;                     // 2,097,152
    ushort_t* Wt      = Xt + 2097152;                       // 196,608
    float*    rowAgg  = (float*)(Wt + 196608);              // 8*24*32*10 = 61,440
    float*    meanArr = rowAgg + 61440;                     // 4800
    float*    rstdArr = meanArr + 4800;                     // 4800

    prep<<<2816, 256, 0, stream>>>(x, conv_w, Xt, Wt);
    conv_gemm<<<dim3(128, 12), 256, 0, stream>>>(Wt, Xt, conv_b, attn, rowAgg);
    gnfin<<<192, 64, 0, stream>>>(rowAgg, meanArr, rstdArr);
    local_attn<<<256, 256, 0, stream>>>(attn, meanArr, rstdArr, gn_w, gn_b, out);
}